// Round 2
// baseline (235.007 us; speedup 1.0000x reference)
//
#include <hip/hip_runtime.h>

#define NPF 16
#define NH 8
#define NV 16
#define NN 900
#define ND 256
#define NB 4

__global__ __launch_bounds__(256, 4) void hough_fused(
    const float* __restrict__ queries,
    const float* __restrict__ cur_ref,
    const float* __restrict__ vote_w,
    const float* __restrict__ vote_b,
    const float* __restrict__ proj_w,
    const float* __restrict__ proj_b,
    float* __restrict__ out)
{
    __shared__ __align__(16) float qs[ND];     // staged query row
    __shared__ float part[256];                // vote partials
    __shared__ float vp[NV * 2];               // vote positions (x,y)*16
    __shared__ float s2i[NV];                  // 1/(2 sigma^2) per v
    __shared__ float row[NN];                  // imap row (pre-normalization)
    __shared__ float red[4];
    __shared__ float s_inv;
    __shared__ __align__(16) float sW[NH * NPF];  // proj weights (broadcast reads)
    __shared__ float sB[NH];

    const int tid = threadIdx.x;
    const int bn  = blockIdx.x;
    const int b   = bn / NN;
    const int n   = bn - b * NN;

    // ---- stage query row + proj weights ----
    qs[tid] = queries[(size_t)bn * ND + tid];
    if (tid < NH * NPF) sW[tid] = proj_w[tid];
    else if (tid < NH * NPF + NH) sB[tid - NH * NPF] = proj_b[tid - NH * NPF];
    __syncthreads();

    // ---- votes: 32 outputs, 8 threads each over D=256 ----
    {
        const int o     = tid & 31;
        const int chunk = tid >> 5;
        const float4* wv = (const float4*)(vote_w + o * ND + chunk * 32);
        const float4* qv = (const float4*)(qs + chunk * 32);
        float p = 0.f;
#pragma unroll
        for (int j = 0; j < 8; j++) {
            float4 w4 = wv[j];
            float4 q4 = qv[j];
            p += w4.x * q4.x + w4.y * q4.y + w4.z * q4.z + w4.w * q4.w;
        }
        part[tid] = p;
    }
    __syncthreads();

    if (tid < 32) {
        float s = vote_b[tid];
#pragma unroll
        for (int c = 0; c < 8; c++) s += part[c * 32 + tid];
        vp[tid] = s + cur_ref[((size_t)b * NN + n) * 4 + (tid & 1)];
    } else if (tid >= 64 && tid < 64 + NV) {
        // sigma quirk: sigma_flat[b, i] = sigma[b, i % N], i = n*V + v
        int v = tid - 64;
        int j = (n * NV + v) % NN;
        float c2 = cur_ref[((size_t)b * NN + j) * 4 + 2];
        float c3 = cur_ref[((size_t)b * NN + j) * 4 + 3];
        float sg = (c2 + c3) * 0.25f;       // mean(c2,c3)/2
        s2i[v] = 0.5f / (sg * sg);
    }
    __syncthreads();

    // ---- folded per-vote coefficients (64 regs live) ----
    // exponent(m,v) = -s2*max(d2,0) = min(C0 + Ax*cx + Ay*cy + nS*cc, 0)
    float Ax[NV], Ay[NV], C0[NV], nS[NV];
#pragma unroll
    for (int v = 0; v < NV; v++) {
        float x  = vp[2 * v];
        float y  = vp[2 * v + 1];
        float s2 = s2i[v];
        Ax[v] = 2.f * s2 * x;
        Ay[v] = 2.f * s2 * y;
        nS[v] = -s2;
        C0[v] = -s2 * (x * x + y * y);
    }

    // ---- imap row ----
    float lsum = 0.f;
    for (int m = tid; m < NN; m += 256) {
        float4 cr = ((const float4*)cur_ref)[(size_t)b * NN + m];
        float cx = cr.x, cy = cr.y;
        float cc = cx * cx + cy * cy;
        float acc = 0.f;
#pragma unroll
        for (int v = 0; v < NV; v++) {
            float t = fmaf(Ax[v], cx, C0[v]);
            t = fmaf(Ay[v], cy, t);
            t = fmaf(nS[v], cc, t);
            acc += __expf(fminf(t, 0.f));
        }
        row[m] = acc;
        lsum += acc;  // acc >= 0 always, |.| redundant
    }

    // ---- block reduce row sum ----
#pragma unroll
    for (int off = 32; off > 0; off >>= 1) lsum += __shfl_down(lsum, off, 64);
    if ((tid & 63) == 0) red[tid >> 6] = lsum;
    __syncthreads();
    if (tid == 0) {
        float s = red[0] + red[1] + red[2] + red[3];
        s_inv = 1.0f / fmaxf(s, 1e-12f);
    }
    __syncthreads();
    const float inv = s_inv;

    // 100 / 10000^(k/8)
    const float invt[8] = {100.0f, 31.622776601683793f, 10.0f, 3.1622776601683795f,
                           1.0f, 0.31622776601683794f, 0.1f, 0.031622776601683791f};

    // ---- epilogue: sine embed + projection + relu ----
    for (int m = tid; m < NN; m += 256) {
        float x = 1.0f - row[m] * inv;
        float sk[8], ck[8];
#pragma unroll
        for (int k = 0; k < 8; k++) {
            float a = x * invt[k];
            sk[k] = __sinf(a);
            ck[k] = __cosf(a);
        }
        float* op = out + (((size_t)(b * NH) * NN + n) * NN + m);
#pragma unroll
        for (int h = 0; h < NH; h++) {
            const float4 w0 = ((const float4*)sW)[h * 4 + 0];  // broadcast ds_read_b128
            const float4 w1 = ((const float4*)sW)[h * 4 + 1];
            const float4 w2 = ((const float4*)sW)[h * 4 + 2];
            const float4 w3 = ((const float4*)sW)[h * 4 + 3];
            float o = sB[h];
            o = fmaf(w0.x, sk[0], o); o = fmaf(w0.y, ck[0], o);
            o = fmaf(w0.z, sk[1], o); o = fmaf(w0.w, ck[1], o);
            o = fmaf(w1.x, sk[2], o); o = fmaf(w1.y, ck[2], o);
            o = fmaf(w1.z, sk[3], o); o = fmaf(w1.w, ck[3], o);
            o = fmaf(w2.x, sk[4], o); o = fmaf(w2.y, ck[4], o);
            o = fmaf(w2.z, sk[5], o); o = fmaf(w2.w, ck[5], o);
            o = fmaf(w3.x, sk[6], o); o = fmaf(w3.y, ck[6], o);
            o = fmaf(w3.z, sk[7], o); o = fmaf(w3.w, ck[7], o);
            op[(size_t)h * NN * NN] = fmaxf(o, 0.f);
        }
    }
}

extern "C" void kernel_launch(void* const* d_in, const int* in_sizes, int n_in,
                              void* d_out, int out_size, void* d_ws, size_t ws_size,
                              hipStream_t stream) {
    const float* queries = (const float*)d_in[0];
    const float* cur_ref = (const float*)d_in[1];
    // d_in[2] = prev_ref_points: unused by the reference
    const float* vote_w  = (const float*)d_in[3];
    const float* vote_b  = (const float*)d_in[4];
    const float* proj_w  = (const float*)d_in[5];
    const float* proj_b  = (const float*)d_in[6];
    float* out = (float*)d_out;

    hough_fused<<<NB * NN, 256, 0, stream>>>(queries, cur_ref, vote_w, vote_b,
                                             proj_w, proj_b, out);
}

// Round 3
// 151.210 us; speedup vs baseline: 1.5542x; 1.5542x over previous
//
#include <hip/hip_runtime.h>

#define NPF 16
#define NH 8
#define NV 16
#define NN 900
#define ND 256
#define NB 4

__global__ __launch_bounds__(256)
__attribute__((amdgpu_waves_per_eu(4, 4)))
void hough_fused(
    const float* __restrict__ queries,
    const float* __restrict__ cur_ref,
    const float* __restrict__ vote_w,
    const float* __restrict__ vote_b,
    const float* __restrict__ proj_w,
    const float* __restrict__ proj_b,
    float* __restrict__ out)
{
    __shared__ __align__(16) float qs[ND];      // staged query row
    __shared__ float part[256];                 // vote partials
    __shared__ float vp[NV * 2];                // vote positions (x,y)*16
    __shared__ float s2i[NV];                   // 1/(2 sigma^2)
    __shared__ __align__(16) float4 sCoef[NV];  // (Ax, Ay, C0, nS) per vote
    __shared__ float red[4];
    __shared__ float s_inv;

    const int tid = threadIdx.x;
    const int bn  = blockIdx.x;
    const int b   = bn / NN;
    const int n   = bn - b * NN;

    // ---- stage query row ----
    qs[tid] = queries[(size_t)bn * ND + tid];
    __syncthreads();

    // ---- votes: 32 outputs, 8 threads each over D=256 ----
    {
        const int o     = tid & 31;
        const int chunk = tid >> 5;
        const float4* wv = (const float4*)(vote_w + o * ND + chunk * 32);
        const float4* qv = (const float4*)(qs + chunk * 32);
        float p = 0.f;
#pragma unroll
        for (int j = 0; j < 8; j++) {
            float4 w4 = wv[j];
            float4 q4 = qv[j];
            p += w4.x * q4.x + w4.y * q4.y + w4.z * q4.z + w4.w * q4.w;
        }
        part[tid] = p;
    }
    __syncthreads();

    if (tid < 32) {
        float s = vote_b[tid];
#pragma unroll
        for (int c = 0; c < 8; c++) s += part[c * 32 + tid];
        vp[tid] = s + cur_ref[((size_t)b * NN + n) * 4 + (tid & 1)];
    } else if (tid >= 64 && tid < 64 + NV) {
        // sigma quirk: sigma_flat[b, i] = sigma[b, i % N], i = n*V + v
        int v = tid - 64;
        int j = (n * NV + v) % NN;
        float c2 = cur_ref[((size_t)b * NN + j) * 4 + 2];
        float c3 = cur_ref[((size_t)b * NN + j) * 4 + 3];
        float sg = (c2 + c3) * 0.25f;       // mean(c2,c3)/2
        s2i[v] = 0.5f / (sg * sg);
    }
    __syncthreads();

    // ---- fold per-vote coefficients: exponent = min(C0 + Ax*cx + Ay*cy + nS*cc, 0)
    if (tid < NV) {
        float x  = vp[2 * tid];
        float y  = vp[2 * tid + 1];
        float s2 = s2i[tid];
        sCoef[tid] = make_float4(2.f * s2 * x, 2.f * s2 * y,
                                 -s2 * (x * x + y * y), -s2);
    }
    __syncthreads();

    // ---- imap: acc[i] for this thread's own m = tid + 256*i, in registers ----
    float acc[4] = {0.f, 0.f, 0.f, 0.f};
    const float4* cr4 = (const float4*)cur_ref + (size_t)b * NN;

#pragma unroll 1
    for (int c = 0; c < 2; c++) {               // two chunks of 8 votes
        float ax[8], ay[8], c0[8], ns[8];
#pragma unroll
        for (int v = 0; v < 8; v++) {
            float4 f = sCoef[c * 8 + v];        // LDS broadcast
            ax[v] = f.x; ay[v] = f.y; c0[v] = f.z; ns[v] = f.w;
        }
#pragma unroll
        for (int i = 0; i < 4; i++) {
            int m = tid + 256 * i;
            if (m < NN) {
                float4 cr = cr4[m];
                float cx = cr.x, cy = cr.y;
                float cc = cx * cx + cy * cy;
                float a = 0.f;
#pragma unroll
                for (int v = 0; v < 8; v++) {
                    float t = fmaf(ax[v], cx, c0[v]);
                    t = fmaf(ay[v], cy, t);
                    t = fmaf(ns[v], cc, t);
                    a += __expf(fminf(t, 0.f));
                }
                acc[i] += a;
            }
        }
    }

    // ---- block reduce row sum (acc >= 0 so |.| is redundant) ----
    float lsum = acc[0] + acc[1] + acc[2] + acc[3];
#pragma unroll
    for (int off = 32; off > 0; off >>= 1) lsum += __shfl_down(lsum, off, 64);
    if ((tid & 63) == 0) red[tid >> 6] = lsum;
    __syncthreads();
    if (tid == 0)
        s_inv = 1.0f / fmaxf(red[0] + red[1] + red[2] + red[3], 1e-12f);
    __syncthreads();
    const float inv = s_inv;

    float xv[4];
#pragma unroll
    for (int i = 0; i < 4; i++) xv[i] = 1.0f - acc[i] * inv;

    // 100 / 10000^(k/8)
    const float invt[8] = {100.0f, 31.622776601683793f, 10.0f, 3.1622776601683795f,
                           1.0f, 0.31622776601683794f, 0.1f, 0.031622776601683791f};

    // ---- epilogue: 2 passes of 4 heads, weights in registers ----
    float* outbase = out + (((size_t)(b * NH) * NN + n) * NN);

#pragma unroll 1
    for (int pass = 0; pass < 2; pass++) {
        float Wr[64];
#pragma unroll
        for (int k = 0; k < 64; k++) Wr[k] = proj_w[pass * 64 + k];  // uniform -> s_load
        float Pb[4];
#pragma unroll
        for (int h = 0; h < 4; h++) Pb[h] = proj_b[pass * 4 + h];

        float* opass = outbase + (size_t)pass * 4 * NN * NN;

#pragma unroll
        for (int i = 0; i < 4; i++) {
            int m = tid + 256 * i;
            if (m < NN) {
                float x = xv[i];
                float sk[8], ck[8];
#pragma unroll
                for (int k = 0; k < 8; k++) {
                    float a = x * invt[k];
                    sk[k] = __sinf(a);
                    ck[k] = __cosf(a);
                }
                float* op = opass + m;
#pragma unroll
                for (int h = 0; h < 4; h++) {
                    float o = Pb[h];
#pragma unroll
                    for (int k = 0; k < 8; k++) {
                        o = fmaf(Wr[h * 16 + 2 * k],     sk[k], o);
                        o = fmaf(Wr[h * 16 + 2 * k + 1], ck[k], o);
                    }
                    op[(size_t)h * NN * NN] = fmaxf(o, 0.f);
                }
            }
        }
    }
}

extern "C" void kernel_launch(void* const* d_in, const int* in_sizes, int n_in,
                              void* d_out, int out_size, void* d_ws, size_t ws_size,
                              hipStream_t stream) {
    const float* queries = (const float*)d_in[0];
    const float* cur_ref = (const float*)d_in[1];
    // d_in[2] = prev_ref_points: unused by the reference
    const float* vote_w  = (const float*)d_in[3];
    const float* vote_b  = (const float*)d_in[4];
    const float* proj_w  = (const float*)d_in[5];
    const float* proj_b  = (const float*)d_in[6];
    float* out = (float*)d_out;

    hough_fused<<<NB * NN, 256, 0, stream>>>(queries, cur_ref, vote_w, vote_b,
                                             proj_w, proj_b, out);
}